// Round 9
// baseline (124.348 us; speedup 1.0000x reference)
//
#include <hip/hip_runtime.h>

#define NEG_SLOPE 0.01f
#define LOG2E 1.4426950408889634f

constexpr int N = 8192;
constexpr int D = 64;
constexpr int NBINS = 8192;
constexpr int NCH = 64;     // chunks
constexpr int CHSZ = 128;   // positions per chunk

// ws float-offsets
constexpr int O_L1  = 0;        // lambda1[N] (log2-domain s1)
constexpr int O_L2  = 8192;     // lambda2[N]
constexpr int O_BMX = 16384;    // per-block max [256]
constexpr int O_BMN = 16640;    // per-block min [256]
constexpr int O_HDR = 16896;    // {lmax, lmin, invw}
constexpr int O_BST = 17024;    // u32 binStart[NBINS+1]
constexpr int O_SL1 = 25600;    // sorted lambda1 [N]
constexpr int O_SB  = 33792;    // Bs[N] = 2^(l1-lmax)
constexpr int O_SD  = 41984;    // Ds[N] = 2^(0.01(l1-lmax))
constexpr int O_SIX = 50176;    // u32 sortedIdx[N]
constexpr int O_LSBS= 58368;    // localSufBs[N] (scalar)
constexpr int O_LPDS= 66560;    // localPreDs[N] (scalar)
constexpr int O_TB  = 74752;    // totB[NCH][D]
constexpr int O_TD  = 78848;    // totD[NCH][D]
constexpr int O_TBS = 82944;    // totBs[NCH]
constexpr int O_TDS = 83008;    // totDs[NCH]
constexpr int O_LSB = 262144;   // localSufB[N][D]  (2MB @ 1MB)
constexpr int O_LPD = 786432;   // localPreD[N][D]  (2MB @ 3MB)

// ---------------- K1: lambda1/lambda2 (log2-scaled) + per-block min/max ----------------
__global__ __launch_bounds__(256) void gat_prep(
    const float* __restrict__ x, const float* __restrict__ W_,
    const float* __restrict__ b, const float* __restrict__ a,
    float* __restrict__ ws) {
  __shared__ float w1s[D], w2s[D], cs[2];
  __shared__ float s1loc[32];
  const int t = threadIdx.x;
  const int bid = blockIdx.x;

  if (t < 128) {
    const int sel = t >> 6, d = t & 63;
    const float* av = a + sel * D;
    float acc = 0.f;
#pragma unroll
    for (int k = 0; k < D; ++k) acc += W_[k * D + d] * av[k];
    (sel ? w2s : w1s)[d] = acc * LOG2E;
  }
  if (t == 128 || t == 129) {
    const int sel = t - 128;
    float acc = 0.f;
    for (int d = 0; d < D; ++d) acc += b[d] * a[sel * D + d];
    cs[sel] = acc * LOG2E;
  }
  __syncthreads();

  {  // 8 threads per row, 32 rows
    const int r = t >> 3, seg = t & 7;
    const int gi = bid * 32 + r;
    const float4 xa = *(const float4*)(x + (size_t)gi * D + seg * 8);
    const float4 xb = *(const float4*)(x + (size_t)gi * D + seg * 8 + 4);
    float p1 = xa.x * w1s[seg * 8 + 0] + xa.y * w1s[seg * 8 + 1] +
               xa.z * w1s[seg * 8 + 2] + xa.w * w1s[seg * 8 + 3] +
               xb.x * w1s[seg * 8 + 4] + xb.y * w1s[seg * 8 + 5] +
               xb.z * w1s[seg * 8 + 6] + xb.w * w1s[seg * 8 + 7];
    float p2 = xa.x * w2s[seg * 8 + 0] + xa.y * w2s[seg * 8 + 1] +
               xa.z * w2s[seg * 8 + 2] + xa.w * w2s[seg * 8 + 3] +
               xb.x * w2s[seg * 8 + 4] + xb.y * w2s[seg * 8 + 5] +
               xb.z * w2s[seg * 8 + 6] + xb.w * w2s[seg * 8 + 7];
#pragma unroll
    for (int off = 4; off; off >>= 1) {
      p1 += __shfl_xor(p1, off, 64);
      p2 += __shfl_xor(p2, off, 64);
    }
    if (seg == 0) {
      const float v1 = p1 + cs[0];
      ws[O_L1 + gi] = v1;
      ws[O_L2 + gi] = p2 + cs[1];
      s1loc[r] = v1;
    }
  }
  __syncthreads();
  if (t == 0) {
    float mx = s1loc[0], mn = s1loc[0];
#pragma unroll
    for (int r = 1; r < 32; ++r) {
      mx = fmaxf(mx, s1loc[r]);
      mn = fminf(mn, s1loc[r]);
    }
    ws[O_BMX + bid] = mx;
    ws[O_BMN + bid] = mn;
  }
}

// ---------------- K2 (1 block x 1024): reduce + counting sort + B/D ----------------
__global__ __launch_bounds__(1024) void gat_sort(float* __restrict__ ws) {
  __shared__ unsigned bins[NBINS];      // 32 KB: counts -> starts -> cursors
  __shared__ float rmx[256], rmn[256];
  __shared__ unsigned waveSum[16], waveBase[16];

  const int t = threadIdx.x;
  const int lane = t & 63;
  const int wid = t >> 6;
  unsigned* binStart = (unsigned*)(ws + O_BST);
  unsigned* sortedIdx = (unsigned*)(ws + O_SIX);

  // reduce block min/max
  if (t < 256) { rmx[t] = ws[O_BMX + t]; rmn[t] = ws[O_BMN + t]; }
  __syncthreads();
  for (int s = 128; s; s >>= 1) {
    if (t < s) {
      rmx[t] = fmaxf(rmx[t], rmx[t + s]);
      rmn[t] = fminf(rmn[t], rmn[t + s]);
    }
    __syncthreads();
  }
  const float lmax = rmx[0], lmin = rmn[0];
  const float invw = (lmax > lmin) ? (float)NBINS / (lmax - lmin) : 0.0f;
  if (t == 0) { ws[O_HDR] = lmax; ws[O_HDR + 1] = lmin; ws[O_HDR + 2] = invw; }

  // zero bins
  for (int q = 0; q < 8; ++q) bins[t * 8 + q] = 0u;
  __syncthreads();

  // histogram (thread t owns elements [8t,8t+8))
  for (int q = 0; q < 8; ++q) {
    const int j = t * 8 + q;
    const float l = ws[O_L1 + j];
    int bb = (int)floorf((l - lmin) * invw);
    bb = bb < 0 ? 0 : (bb > NBINS - 1 ? NBINS - 1 : bb);
    atomicAdd(&bins[bb], 1u);
  }
  __syncthreads();

  // exclusive scan of bins (thread t owns bins [8t,8t+8))
  unsigned loc[8], s = 0;
#pragma unroll
  for (int q = 0; q < 8; ++q) { loc[q] = bins[t * 8 + q]; s += loc[q]; }
  unsigned v = s;
#pragma unroll
  for (int off = 1; off < 64; off <<= 1) {
    unsigned n = __shfl_up((int)v, off, 64);
    if (lane >= off) v += n;
  }
  if (lane == 63) waveSum[wid] = v;
  __syncthreads();
  if (t == 0) {
    unsigned run = 0;
    for (int w2 = 0; w2 < 16; ++w2) { waveBase[w2] = run; run += waveSum[w2]; }
  }
  __syncthreads();
  unsigned run = waveBase[wid] + (v - s);  // exclusive-of-this-thread
#pragma unroll
  for (int q = 0; q < 8; ++q) {
    bins[t * 8 + q] = run;
    binStart[t * 8 + q] = run;
    run += loc[q];
  }
  if (t == 0) binStart[NBINS] = (unsigned)N;
  __syncthreads();

  // scatter (bins[] now cursors) + B/D
  for (int q = 0; q < 8; ++q) {
    const int j = t * 8 + q;
    const float l = ws[O_L1 + j];
    int bb = (int)floorf((l - lmin) * invw);
    bb = bb < 0 ? 0 : (bb > NBINS - 1 ? NBINS - 1 : bb);
    const unsigned pos = atomicAdd(&bins[bb], 1u);
    ws[O_SL1 + pos] = l;
    sortedIdx[pos] = (unsigned)j;
    const float e = l - lmax;
    ws[O_SB + pos] = exp2f(e);
    ws[O_SD + pos] = exp2f(0.01f * e);
  }
}

// ---------------- K3 (64 blocks x 256): chunk-local scans + chunk totals ----------------
__global__ __launch_bounds__(256) void gat_scan(
    const float* __restrict__ x, float* __restrict__ ws) {
  __shared__ float xl[CHSZ][D];   // 32 KB staged gathered rows
  __shared__ float BsL[CHSZ], DsL[CHSZ];

  const int t = threadIdx.x;
  const int c = blockIdx.x;
  const unsigned* sortedIdx = (const unsigned*)(ws + O_SIX);
  __shared__ unsigned idsL[CHSZ];

  if (t < CHSZ) {
    const int pos = c * CHSZ + t;
    idsL[t] = sortedIdx[pos];
    BsL[t] = ws[O_SB + pos];
    DsL[t] = ws[O_SD + pos];
  }
  __syncthreads();
  // stage 128 gathered x rows (coalesced per row)
#pragma unroll
  for (int q = 0; q < 32; ++q) {
    const int lin = q * 256 + t;
    const int row = lin >> 6, d = lin & 63;
    xl[row][d] = x[(size_t)idsL[row] * D + d];
  }
  __syncthreads();

  const int lane = t & 63;
  const int wid = t >> 6;
  if (wid == 0) {  // ascending exclusive prefix of D*x
    float runD = 0.f, runDs = 0.f;
    for (int k = 0; k < CHSZ; ++k) {
      const int pos = c * CHSZ + k;
      ws[O_LPD + (size_t)pos * D + lane] = runD;
      if (lane == 0) ws[O_LPDS + pos] = runDs;
      const float dk = DsL[k];
      runD = fmaf(dk, xl[k][lane], runD);
      runDs += dk;
    }
    ws[O_TD + c * D + lane] = runD;
    if (lane == 0) ws[O_TDS + c] = runDs;
  } else if (wid == 1) {  // descending inclusive suffix of B*x
    float runB = 0.f, runBs = 0.f;
    for (int k = CHSZ - 1; k >= 0; --k) {
      const int pos = c * CHSZ + k;
      const float bk = BsL[k];
      runB = fmaf(bk, xl[k][lane], runB);
      runBs += bk;
      ws[O_LSB + (size_t)pos * D + lane] = runB;
      if (lane == 0) ws[O_LSBS + pos] = runBs;
    }
    ws[O_TB + c * D + lane] = runB;
    if (lane == 0) ws[O_TBS + c] = runBs;
  }
}

// ---------------- K4 (256 blocks x 256): per-row combine ----------------
__global__ __launch_bounds__(256) void gat_out(
    const float* __restrict__ x, float* __restrict__ ws,
    float* __restrict__ out) {
  __shared__ float preTotD[NCH + 1][D];  // 16.6 KB
  __shared__ float sufTotB[NCH + 1][D];  // 16.6 KB
  __shared__ float sTotD[NCH + 1], sTotB[NCH + 1];

  const int t = threadIdx.x;
  const int lane = t & 63;
  const int wid = t >> 6;
  const unsigned* binStart = (const unsigned*)(ws + O_BST);
  const unsigned* sortedIdx = (const unsigned*)(ws + O_SIX);

  const float lmax = ws[O_HDR], lmin = ws[O_HDR + 1], invw = ws[O_HDR + 2];

  if (wid == 0) {  // chunk-total scans, lane = dim
    float rp = 0.f;
    for (int c = 0; c < NCH; ++c) {
      preTotD[c][lane] = rp;
      rp += ws[O_TD + c * D + lane];
    }
    preTotD[NCH][lane] = rp;
    float rs = 0.f;
    sufTotB[NCH][lane] = 0.f;
    for (int c = NCH - 1; c >= 0; --c) {
      rs += ws[O_TB + c * D + lane];
      sufTotB[c][lane] = rs;
    }
  } else if (t == 64) {  // scalar totals
    float rp = 0.f;
    for (int c = 0; c < NCH; ++c) { sTotD[c] = rp; rp += ws[O_TDS + c]; }
    sTotD[NCH] = rp;
    float rs = 0.f;
    sTotB[NCH] = 0.f;
    for (int c = NCH - 1; c >= 0; --c) { rs += ws[O_TBS + c]; sTotB[c] = rs; }
  }
  __syncthreads();

  for (int q = 0; q < 8; ++q) {
    const int i = blockIdx.x * 32 + wid * 8 + q;
    const float l2 = ws[O_L2 + i];
    const float th = -l2;                  // pos-branch: l1 >= th
    const float tm = l2 + lmax;
    const float mu = fmaxf(tm, NEG_SLOPE * tm);
    const float cA = exp2f(tm - mu);
    const float cC = exp2f(NEG_SLOPE * tm - mu);

    int bb = (int)floorf((th - lmin) * invw);
    bb = bb < 0 ? 0 : (bb > NBINS - 1 ? NBINS - 1 : bb);
    const int pos0 = (int)binStart[bb];
    const int pos1 = (int)binStart[bb + 1];

    float sB, sBs, pD, pDs;
    if (pos1 < N) {
      sB = ws[O_LSB + (size_t)pos1 * D + lane] + sufTotB[(pos1 >> 7) + 1][lane];
      sBs = ws[O_LSBS + pos1] + sTotB[(pos1 >> 7) + 1];
    } else { sB = 0.f; sBs = 0.f; }
    if (pos0 < N) {
      pD = ws[O_LPD + (size_t)pos0 * D + lane] + preTotD[pos0 >> 7][lane];
      pDs = ws[O_LPDS + pos0] + sTotD[pos0 >> 7];
    } else { pD = preTotD[NCH][lane]; pDs = sTotD[NCH]; }

    // straddling bin: exact per-element classification
    for (int k = pos0; k < pos1; ++k) {
      const float lk = ws[O_SL1 + k];
      const float xv = x[(size_t)sortedIdx[k] * D + lane];
      const float bk = ws[O_SB + k], dk = ws[O_SD + k];
      if (lk >= th) { sB = fmaf(bk, xv, sB); sBs += bk; }
      else          { pD = fmaf(dk, xv, pD); pDs += dk; }
    }

    const float num = cA * sB + cC * pD;
    const float den = cA * sBs + cC * pDs;
    out[(size_t)i * D + lane] = num / den;
  }
}

extern "C" void kernel_launch(void* const* d_in, const int* in_sizes, int n_in,
                              void* d_out, int out_size, void* d_ws, size_t ws_size,
                              hipStream_t stream) {
  const float* x = (const float*)d_in[0];   // 8192*64 f32
  const float* W = (const float*)d_in[1];   // 64*64
  const float* b = (const float*)d_in[2];   // 64
  const float* a = (const float*)d_in[3];   // 128
  float* ws = (float*)d_ws;
  float* out = (float*)d_out;

  gat_prep<<<N / 32, 256, 0, stream>>>(x, W, b, a, ws);
  gat_sort<<<1, 1024, 0, stream>>>(ws);
  gat_scan<<<NCH, 256, 0, stream>>>(x, ws);
  gat_out<<<N / 32, 256, 0, stream>>>(x, ws, out);
}